// Round 3
// baseline (191.813 us; speedup 1.0000x reference)
//
#include <hip/hip_runtime.h>
#include <hip/hip_bf16.h>

#define PIX 256
#define CROP 14
#define HW2 196
#define BB 128
#define CC 512
#define NC 384
#define NO 768
#define CAP 128

typedef __bf16 bf16x8 __attribute__((ext_vector_type(8)));
typedef __bf16 bf16x4 __attribute__((ext_vector_type(4)));
typedef float  f32x4  __attribute__((ext_vector_type(4)));
typedef unsigned int u32;

#define GLOAD_LDS16(src, dst) \
    __builtin_amdgcn_global_load_lds((const __attribute__((address_space(1))) void*)(src), \
                                     (__attribute__((address_space(3))) void*)(dst), 16, 0, 0)

__global__ void wconv_kernel(const float* __restrict__ W, __bf16* __restrict__ Wb) {
    int tid = blockIdx.x * 256 + threadIdx.x;
    Wb[tid] = (__bf16)W[tid];
}

__global__ void fill_kernel(const int* __restrict__ idx, const int* __restrict__ offh,
                            const int* __restrict__ offw, int* __restrict__ cnt,
                            u32* __restrict__ bucket) {
    int tid = blockIdx.x * 256 + threadIdx.x;
    int c3 = tid / HW2;
    int hw = tid - c3 * HW2;
    int i = hw / CROP, j = hw - i * CROP;
    int p = (offh[c3] + i) * 16 + offw[c3] + j;
    int ch = idx[c3 * PIX + p];
    int bkt = (c3 >> 7) * CC + ch;
    int pos = atomicAdd(&cnt[bkt], 1);
    if (pos < CAP) bucket[bkt * CAP + pos] = ((u32)c3 << 16) | ((u32)hw << 8) | (u32)p;
}

#define LSTR 260
__global__ __launch_bounds__(256) void scatter_kernel(
        const float* __restrict__ x1, const float* __restrict__ x3,
        const float* __restrict__ x5, const int* __restrict__ cnt,
        const u32* __restrict__ bucket, __bf16* __restrict__ fT) {
    __shared__ __bf16 lds[64 * LSTR];
    int bx = blockIdx.x;
    int E = cnt[bx]; if (E > CAP) E = CAP;
    if (E == 0) return;
    int b0 = blockIdx.y * 64;
    int t = bx >> 9, ch = bx & 511;
    const float* x = (t == 0) ? x1 : (t == 1) ? x3 : x5;
    int w = threadIdx.x >> 6, lane = threadIdx.x & 63;
    for (int r = w; r < 64; r += 4) {
        f32x4 v = *(const f32x4*)(x + ((size_t)(b0 + r) * CC + ch) * PIX + lane * 4);
        bf16x4 q;
        q[0] = (__bf16)v[0]; q[1] = (__bf16)v[1]; q[2] = (__bf16)v[2]; q[3] = (__bf16)v[3];
        *(bf16x4*)&lds[r * LSTR + lane * 4] = q;
    }
    __syncthreads();
    for (int e = w; e < E; e += 4) {
        u32 pk = bucket[bx * CAP + e];
        int c3 = pk >> 16, hw = (pk >> 8) & 255, p = pk & 255;
        fT[((size_t)c3 * HW2 + hw) * BB + b0 + lane] = lds[lane * LSTR + p];
    }
}

__global__ __launch_bounds__(256) void ftrans_kernel(const __bf16* __restrict__ fT,
                                                     __bf16* __restrict__ feats) {
    __shared__ __bf16 lds[64 * 128];
    int hw = blockIdx.x;
    int c0 = blockIdx.y * 64;
    int t = threadIdx.x;
    int l16 = t & 15;
#pragma unroll
    for (int r4 = 0; r4 < 4; ++r4) {
        int cr = (t >> 4) + r4 * 16;
        bf16x8 v = *(const bf16x8*)(fT + ((size_t)(c0 + cr) * HW2 + hw) * BB + l16 * 8);
        int chunk = l16 ^ ((cr >> 3) & 7);
        *(bf16x8*)&lds[cr * 128 + chunk * 8] = v;
    }
    __syncthreads();
    int cg = t & 7;
#pragma unroll
    for (int r = 0; r < 4; ++r) {
        int b = (t >> 3) + r * 32;
        bf16x8 ov;
#pragma unroll
        for (int k = 0; k < 8; ++k) {
            int c = cg * 8 + k;
            ov[k] = lds[c * 128 + (((b >> 3) ^ cg) * 8) + (b & 7)];
        }
        *(bf16x8*)(feats + ((size_t)b * HW2 + hw) * NC + c0 + cg * 8) = ov;
    }
}

// GEMM: out[b,o,hw] = sum_c W[o,c] * feats[(b*196+hw)][c]
// Block: 512 thr = 8 waves (4o x 2m), tile o=256 x m=128, BK=64.
// LDS 48KB single-buffer (A 32KB + B 16KB) -> 3 blocks/CU. global_load_lds w=16,
// k-chunk XOR swizzle via pre-swizzled global source (linear LDS dest).
__global__ __launch_bounds__(512, 6) void gemm_kernel(const __bf16* __restrict__ feats,
                                                      const __bf16* __restrict__ Wb,
                                                      float* __restrict__ out) {
    __shared__ __bf16 ldsbuf[24576];           // A [256][64] @0, B [128][64] @16384
    __bf16* Abuf = ldsbuf;
    __bf16* Bbuf = ldsbuf + 16384;

    // bijective XCD-chunked swizzle (588 blocks, 8 XCDs): consecutive wg on one XCD
    const int d = blockIdx.x;                  // 0..587
    const int q = 588 / 8, r = 588 % 8;        // 73, 4
    const int xcd = d & 7, slot = d >> 3;
    const int wg = (xcd < r ? xcd * (q + 1) : r * (q + 1) + (xcd - r) * q) + slot;
    const int o_base = (wg % 3) * 256;
    const int m_base = (wg / 3) * 128;

    const int tid = threadIdx.x;
    const int wave = tid >> 6, lane = tid & 63;
    const int wo = wave >> 1, wm = wave & 1;
    const int l15 = lane & 15, g = lane >> 4;
    const int subrow = lane >> 3;                       // 0..7 within 8-row group
    const int kperm = ((lane & 7) ^ subrow) * 8;        // pre-swizzled source k-offset
    const int xr = l15 & 7;

    f32x4 acc[4][4] = {};

    for (int kt = 0; kt < 6; ++kt) {
        const int k0g = kt * 64;
        // stage: 48 x 1KB instrs total, 6 per wave (A: j<32, B: j>=32)
#pragma unroll
        for (int jj = 0; jj < 6; ++jj) {
            int j = wave * 6 + jj;
            if (j < 32) {
                const __bf16* src = Wb + (size_t)(o_base + j * 8 + subrow) * NC + k0g + kperm;
                GLOAD_LDS16(src, Abuf + j * 512);
            } else {
                const __bf16* src = feats + (size_t)(m_base + (j - 32) * 8 + subrow) * NC + k0g + kperm;
                GLOAD_LDS16(src, Bbuf + (j - 32) * 512);
            }
        }
        __syncthreads();
#pragma unroll
        for (int k0 = 0; k0 < 64; k0 += 32) {
            const int cb = (k0 >> 3) + g;
            bf16x8 a[4], b[4];
#pragma unroll
            for (int s = 0; s < 4; ++s) {
                int arow = wo * 64 + s * 16 + l15;
                a[s] = *(const bf16x8*)&Abuf[arow * 64 + ((cb ^ xr) << 3)];
                int brow = wm * 64 + s * 16 + l15;
                b[s] = *(const bf16x8*)&Bbuf[brow * 64 + ((cb ^ xr) << 3)];
            }
#pragma unroll
            for (int os = 0; os < 4; ++os)
#pragma unroll
                for (int ms = 0; ms < 4; ++ms)
                    acc[os][ms] = __builtin_amdgcn_mfma_f32_16x16x32_bf16(a[os], b[ms], acc[os][ms], 0, 0, 0);
        }
        __syncthreads();
    }

#pragma unroll
    for (int os = 0; os < 4; ++os)
#pragma unroll
        for (int ms = 0; ms < 4; ++ms) {
            int m = m_base + wm * 64 + ms * 16 + l15;
            int bb = m / HW2;
            int hw = m - bb * HW2;
            int o = o_base + wo * 64 + os * 16 + g * 4;
            float* dst = out + ((size_t)bb * NO + o) * HW2 + hw;
            f32x4 v = acc[os][ms];
            dst[0 * HW2] = v[0];
            dst[1 * HW2] = v[1];
            dst[2 * HW2] = v[2];
            dst[3 * HW2] = v[3];
        }
}

extern "C" void kernel_launch(void* const* d_in, const int* in_sizes, int n_in,
                              void* d_out, int out_size, void* d_ws, size_t ws_size,
                              hipStream_t stream) {
    const float* x1   = (const float*)d_in[0];
    const float* x3   = (const float*)d_in[1];
    const float* x5   = (const float*)d_in[2];
    const float* W    = (const float*)d_in[3];
    const int*   idx  = (const int*)d_in[4];
    const int*   offh = (const int*)d_in[5];
    const int*   offw = (const int*)d_in[6];
    float* out = (float*)d_out;

    char* ws = (char*)d_ws;
    __bf16* fT     = (__bf16*)(ws);              // 19,267,584 B
    __bf16* feats  = (__bf16*)(ws + 19267584);   // 19,267,584 B
    __bf16* Wb     = (__bf16*)(ws + 38535168);   // 589,824 B
    int*    cnt    = (int*)   (ws + 39124992);   // 6,144 B
    u32*    bucket = (u32*)   (ws + 39131136);   // 786,432 B

    wconv_kernel<<<(NO * NC) / 256, 256, 0, stream>>>(W, Wb);
    hipMemsetAsync(cnt, 0, 1536 * sizeof(int), stream);
    fill_kernel<<<(NC * HW2) / 256, 256, 0, stream>>>(idx, offh, offw, cnt, bucket);
    scatter_kernel<<<dim3(1536, 2), 256, 0, stream>>>(x1, x3, x5, cnt, bucket, fT);
    ftrans_kernel<<<dim3(HW2, 6), 256, 0, stream>>>(fT, feats);
    gemm_kernel<<<588, 512, 0, stream>>>(feats, Wb, out);
}

// Round 4
// 110.281 us; speedup vs baseline: 1.7393x; 1.7393x over previous
//
#include <hip/hip_runtime.h>
#include <hip/hip_bf16.h>

#define PIX 256
#define CROP 14
#define HW2 196
#define BB 128
#define CC 512
#define NC 384
#define NO 768
#define CAP 128

typedef __bf16 bf16x8 __attribute__((ext_vector_type(8)));
typedef __bf16 bf16x4 __attribute__((ext_vector_type(4)));
typedef float  f32x4  __attribute__((ext_vector_type(4)));
typedef unsigned int u32;

#define GLOAD_LDS16(src, dst) \
    __builtin_amdgcn_global_load_lds((const __attribute__((address_space(1))) void*)(src), \
                                     (__attribute__((address_space(3))) void*)(dst), 16, 0, 0)

__global__ void wconv_kernel(const float* __restrict__ W, __bf16* __restrict__ Wb) {
    int tid = blockIdx.x * 256 + threadIdx.x;
    Wb[tid] = (__bf16)W[tid];
}

__global__ void fill_kernel(const int* __restrict__ idx, const int* __restrict__ offh,
                            const int* __restrict__ offw, int* __restrict__ cnt,
                            u32* __restrict__ bucket) {
    int tid = blockIdx.x * 256 + threadIdx.x;
    int c3 = tid / HW2;
    int hw = tid - c3 * HW2;
    int i = hw / CROP, j = hw - i * CROP;
    int p = (offh[c3] + i) * 16 + offw[c3] + j;
    int ch = idx[c3 * PIX + p];
    int bkt = (c3 >> 7) * CC + ch;
    int pos = atomicAdd(&cnt[bkt], 1);
    if (pos < CAP) bucket[bkt * CAP + pos] = ((u32)c3 << 16) | ((u32)hw << 8) | (u32)p;
}

#define LSTR 260
__global__ __launch_bounds__(256) void scatter_kernel(
        const float* __restrict__ x1, const float* __restrict__ x3,
        const float* __restrict__ x5, const int* __restrict__ cnt,
        const u32* __restrict__ bucket, __bf16* __restrict__ fT) {
    __shared__ __bf16 lds[64 * LSTR];
    int bx = blockIdx.x;
    int E = cnt[bx]; if (E > CAP) E = CAP;
    if (E == 0) return;
    int b0 = blockIdx.y * 64;
    int t = bx >> 9, ch = bx & 511;
    const float* x = (t == 0) ? x1 : (t == 1) ? x3 : x5;
    int w = threadIdx.x >> 6, lane = threadIdx.x & 63;
    for (int r = w; r < 64; r += 4) {
        f32x4 v = *(const f32x4*)(x + ((size_t)(b0 + r) * CC + ch) * PIX + lane * 4);
        bf16x4 q;
        q[0] = (__bf16)v[0]; q[1] = (__bf16)v[1]; q[2] = (__bf16)v[2]; q[3] = (__bf16)v[3];
        *(bf16x4*)&lds[r * LSTR + lane * 4] = q;
    }
    __syncthreads();
    for (int e = w; e < E; e += 4) {
        u32 pk = bucket[bx * CAP + e];
        int c3 = pk >> 16, hw = (pk >> 8) & 255, p = pk & 255;
        fT[((size_t)c3 * HW2 + hw) * BB + b0 + lane] = lds[lane * LSTR + p];
    }
}

__global__ __launch_bounds__(256) void ftrans_kernel(const __bf16* __restrict__ fT,
                                                     __bf16* __restrict__ feats) {
    __shared__ __bf16 lds[64 * 128];
    int hw = blockIdx.x;
    int c0 = blockIdx.y * 64;
    int t = threadIdx.x;
    int l16 = t & 15;
#pragma unroll
    for (int r4 = 0; r4 < 4; ++r4) {
        int cr = (t >> 4) + r4 * 16;
        bf16x8 v = *(const bf16x8*)(fT + ((size_t)(c0 + cr) * HW2 + hw) * BB + l16 * 8);
        int chunk = l16 ^ ((cr >> 3) & 7);
        *(bf16x8*)&lds[cr * 128 + chunk * 8] = v;
    }
    __syncthreads();
    int cg = t & 7;
#pragma unroll
    for (int r = 0; r < 4; ++r) {
        int b = (t >> 3) + r * 32;
        bf16x8 ov;
#pragma unroll
        for (int k = 0; k < 8; ++k) {
            int c = cg * 8 + k;
            ov[k] = lds[c * 128 + (((b >> 3) ^ cg) * 8) + (b & 7)];
        }
        *(bf16x8*)(feats + ((size_t)b * HW2 + hw) * NC + c0 + cg * 8) = ov;
    }
}

// GEMM: out[b,o,hw] = sum_c W[o,c] * feats[(b*196+hw)][c]
// m97 structure: 256 thr = 4 waves (2o x 2m), tile o=128 x m=128, BK=64,
// LDS 32KB single-buffer, global_load_lds w=16, XOR-swizzled k-chunks
// (pre-swizzled global source, linear LDS dest, swizzled ds_read).
// No forced min-waves: VGPR ~160 -> 3 blocks/CU (12 waves/CU).
__global__ __launch_bounds__(256) void gemm_kernel(const __bf16* __restrict__ feats,
                                                   const __bf16* __restrict__ Wb,
                                                   float* __restrict__ out) {
    __shared__ __bf16 ldsbuf[16384];           // A [128][64] @0, B [128][64] @8192
    __bf16* Abuf = ldsbuf;
    __bf16* Bbuf = ldsbuf + 8192;

    // bijective XCD swizzle: 1176 blocks, 1176 % 8 == 0, 147 per XCD
    const int d = blockIdx.x;
    const int wg = (d & 7) * 147 + (d >> 3);
    const int o_base = (wg % 6) * 128;         // 6 consecutive wg share the m-tile
    const int m_base = (wg / 6) * 128;

    const int tid = threadIdx.x;
    const int wave = tid >> 6, lane = tid & 63;
    const int wo = wave >> 1, wm = wave & 1;
    const int l15 = lane & 15, g = lane >> 4;
    const int xr = l15 & 7;

    f32x4 acc[4][4] = {};

    for (int kt = 0; kt < 6; ++kt) {
        const int k0g = kt * 64;
        // stage 128 rows x 8 chunks (16B) for A and B: 4 iters x 256 thr each
#pragma unroll
        for (int it = 0; it < 4; ++it) {
            int ck = tid + it * 256;           // 0..1023
            int row = ck >> 3, cc = ck & 7;
            int koff = k0g + ((cc ^ (row & 7)) << 3);   // pre-swizzled source
            GLOAD_LDS16(Wb    + (size_t)(o_base + row) * NC + koff, Abuf + ck * 8);
            GLOAD_LDS16(feats + (size_t)(m_base + row) * NC + koff, Bbuf + ck * 8);
        }
        __syncthreads();
#pragma unroll
        for (int k0 = 0; k0 < 64; k0 += 32) {
            const int cb = (k0 >> 3) + g;
            bf16x8 a[4], b[4];
#pragma unroll
            for (int s = 0; s < 4; ++s) {
                int arow = wo * 64 + s * 16 + l15;
                a[s] = *(const bf16x8*)&Abuf[arow * 64 + ((cb ^ xr) << 3)];
                int brow = wm * 64 + s * 16 + l15;
                b[s] = *(const bf16x8*)&Bbuf[brow * 64 + ((cb ^ xr) << 3)];
            }
#pragma unroll
            for (int os = 0; os < 4; ++os)
#pragma unroll
                for (int ms = 0; ms < 4; ++ms)
                    acc[os][ms] = __builtin_amdgcn_mfma_f32_16x16x32_bf16(a[os], b[ms], acc[os][ms], 0, 0, 0);
        }
        __syncthreads();
    }

#pragma unroll
    for (int os = 0; os < 4; ++os)
#pragma unroll
        for (int ms = 0; ms < 4; ++ms) {
            int m = m_base + wm * 64 + ms * 16 + l15;
            int bb = m / HW2;
            int hw = m - bb * HW2;
            int o = o_base + wo * 64 + os * 16 + g * 4;
            float* dst = out + ((size_t)bb * NO + o) * HW2 + hw;
            f32x4 v = acc[os][ms];
            dst[0 * HW2] = v[0];
            dst[1 * HW2] = v[1];
            dst[2 * HW2] = v[2];
            dst[3 * HW2] = v[3];
        }
}

extern "C" void kernel_launch(void* const* d_in, const int* in_sizes, int n_in,
                              void* d_out, int out_size, void* d_ws, size_t ws_size,
                              hipStream_t stream) {
    const float* x1   = (const float*)d_in[0];
    const float* x3   = (const float*)d_in[1];
    const float* x5   = (const float*)d_in[2];
    const float* W    = (const float*)d_in[3];
    const int*   idx  = (const int*)d_in[4];
    const int*   offh = (const int*)d_in[5];
    const int*   offw = (const int*)d_in[6];
    float* out = (float*)d_out;

    char* ws = (char*)d_ws;
    __bf16* fT     = (__bf16*)(ws);              // 19,267,584 B
    __bf16* feats  = (__bf16*)(ws + 19267584);   // 19,267,584 B
    __bf16* Wb     = (__bf16*)(ws + 38535168);   // 589,824 B
    int*    cnt    = (int*)   (ws + 39124992);   // 6,144 B
    u32*    bucket = (u32*)   (ws + 39131136);   // 786,432 B

    wconv_kernel<<<(NO * NC) / 256, 256, 0, stream>>>(W, Wb);
    hipMemsetAsync(cnt, 0, 1536 * sizeof(int), stream);
    fill_kernel<<<(NC * HW2) / 256, 256, 0, stream>>>(idx, offh, offw, cnt, bucket);
    scatter_kernel<<<dim3(1536, 2), 256, 0, stream>>>(x1, x3, x5, cnt, bucket, fT);
    ftrans_kernel<<<dim3(HW2, 6), 256, 0, stream>>>(fT, feats);
    gemm_kernel<<<1176, 256, 0, stream>>>(feats, Wb, out);
}

// Round 5
// 107.992 us; speedup vs baseline: 1.7762x; 1.0212x over previous
//
#include <hip/hip_runtime.h>
#include <hip/hip_bf16.h>

#define PIX 256
#define CROP 14
#define HW2 196
#define BB 128
#define CC 512
#define NC 384
#define NO 768
#define CAP 128

typedef __bf16 bf16x8 __attribute__((ext_vector_type(8)));
typedef __bf16 bf16x4 __attribute__((ext_vector_type(4)));
typedef float  f32x4  __attribute__((ext_vector_type(4)));
typedef unsigned int u32;

#define GLOAD_LDS16(src, dst) \
    __builtin_amdgcn_global_load_lds((const __attribute__((address_space(1))) void*)(src), \
                                     (__attribute__((address_space(3))) void*)(dst), 16, 0, 0)

__global__ void wconv_kernel(const float* __restrict__ W, __bf16* __restrict__ Wb) {
    int tid = blockIdx.x * 256 + threadIdx.x;
    Wb[tid] = (__bf16)W[tid];
}

__global__ void fill_kernel(const int* __restrict__ idx, const int* __restrict__ offh,
                            const int* __restrict__ offw, int* __restrict__ cnt,
                            u32* __restrict__ bucket) {
    int tid = blockIdx.x * 256 + threadIdx.x;
    int c3 = tid / HW2;
    int hw = tid - c3 * HW2;
    int i = hw / CROP, j = hw - i * CROP;
    int p = (offh[c3] + i) * 16 + offw[c3] + j;
    int ch = idx[c3 * PIX + p];
    int bkt = (c3 >> 7) * CC + ch;
    int pos = atomicAdd(&cnt[bkt], 1);
    if (pos < CAP) bucket[bkt * CAP + pos] = ((u32)c3 << 16) | ((u32)hw << 8) | (u32)p;
}

// 32 b-rows per block -> LDS 16.6KB -> 8 blocks/CU (32 waves/CU, occupancy cap).
// Each wave-iteration scatters 2 bucket entries (half-wave = 32 contiguous b).
#define LSTR 260
__global__ __launch_bounds__(256) void scatter_kernel(
        const float* __restrict__ x1, const float* __restrict__ x3,
        const float* __restrict__ x5, const int* __restrict__ cnt,
        const u32* __restrict__ bucket, __bf16* __restrict__ fT) {
    __shared__ __bf16 lds[32 * LSTR];
    int bx = blockIdx.x;                 // t*512 + ch
    int E = cnt[bx]; if (E > CAP) E = CAP;
    if (E == 0) return;
    int b0 = blockIdx.y * 32;
    int t = bx >> 9, ch = bx & 511;
    const float* x = (t == 0) ? x1 : (t == 1) ? x3 : x5;
    int w = threadIdx.x >> 6, lane = threadIdx.x & 63;
    // stage rows x[b0+r][ch][0..255] as bf16 (1KB coalesced per wave-instr)
    for (int r = w; r < 32; r += 4) {
        f32x4 v = *(const f32x4*)(x + ((size_t)(b0 + r) * CC + ch) * PIX + lane * 4);
        bf16x4 q;
        q[0] = (__bf16)v[0]; q[1] = (__bf16)v[1]; q[2] = (__bf16)v[2]; q[3] = (__bf16)v[3];
        *(bf16x4*)&lds[r * LSTR + lane * 4] = q;
    }
    __syncthreads();
    int half = lane >> 5, bl = lane & 31;
    for (int e = w * 2 + half; e < E; e += 8) {
        u32 pk = bucket[bx * CAP + e];
        int c3 = pk >> 16, hw = (pk >> 8) & 255, p = pk & 255;
        fT[((size_t)c3 * HW2 + hw) * BB + b0 + bl] = lds[bl * LSTR + p];
    }
}

__global__ __launch_bounds__(256) void ftrans_kernel(const __bf16* __restrict__ fT,
                                                     __bf16* __restrict__ feats) {
    __shared__ __bf16 lds[64 * 128];
    int hw = blockIdx.x;
    int c0 = blockIdx.y * 64;
    int t = threadIdx.x;
    int l16 = t & 15;
#pragma unroll
    for (int r4 = 0; r4 < 4; ++r4) {
        int cr = (t >> 4) + r4 * 16;
        bf16x8 v = *(const bf16x8*)(fT + ((size_t)(c0 + cr) * HW2 + hw) * BB + l16 * 8);
        int chunk = l16 ^ ((cr >> 3) & 7);
        *(bf16x8*)&lds[cr * 128 + chunk * 8] = v;
    }
    __syncthreads();
    int cg = t & 7;
#pragma unroll
    for (int r = 0; r < 4; ++r) {
        int b = (t >> 3) + r * 32;
        bf16x8 ov;
#pragma unroll
        for (int k = 0; k < 8; ++k) {
            int c = cg * 8 + k;
            ov[k] = lds[c * 128 + (((b >> 3) ^ cg) * 8) + (b & 7)];
        }
        *(bf16x8*)(feats + ((size_t)b * HW2 + hw) * NC + c0 + cg * 8) = ov;
    }
}

// GEMM: m97 structure, 128x128 tile, BK=64, XOR-swizzled LDS via pre-swizzled source.
__global__ __launch_bounds__(256) void gemm_kernel(const __bf16* __restrict__ feats,
                                                   const __bf16* __restrict__ Wb,
                                                   float* __restrict__ out) {
    __shared__ __bf16 ldsbuf[16384];           // A [128][64] @0, B [128][64] @8192
    __bf16* Abuf = ldsbuf;
    __bf16* Bbuf = ldsbuf + 8192;

    const int d = blockIdx.x;                  // 1176 blocks, 147 per XCD
    const int wg = (d & 7) * 147 + (d >> 3);
    const int o_base = (wg % 6) * 128;
    const int m_base = (wg / 6) * 128;

    const int tid = threadIdx.x;
    const int wave = tid >> 6, lane = tid & 63;
    const int wo = wave >> 1, wm = wave & 1;
    const int l15 = lane & 15, g = lane >> 4;
    const int xr = l15 & 7;

    f32x4 acc[4][4] = {};

    for (int kt = 0; kt < 6; ++kt) {
        const int k0g = kt * 64;
#pragma unroll
        for (int it = 0; it < 4; ++it) {
            int ck = tid + it * 256;
            int row = ck >> 3, cc = ck & 7;
            int koff = k0g + ((cc ^ (row & 7)) << 3);
            GLOAD_LDS16(Wb    + (size_t)(o_base + row) * NC + koff, Abuf + ck * 8);
            GLOAD_LDS16(feats + (size_t)(m_base + row) * NC + koff, Bbuf + ck * 8);
        }
        __syncthreads();
#pragma unroll
        for (int k0 = 0; k0 < 64; k0 += 32) {
            const int cb = (k0 >> 3) + g;
            bf16x8 a[4], b[4];
#pragma unroll
            for (int s = 0; s < 4; ++s) {
                int arow = wo * 64 + s * 16 + l15;
                a[s] = *(const bf16x8*)&Abuf[arow * 64 + ((cb ^ xr) << 3)];
                int brow = wm * 64 + s * 16 + l15;
                b[s] = *(const bf16x8*)&Bbuf[brow * 64 + ((cb ^ xr) << 3)];
            }
#pragma unroll
            for (int os = 0; os < 4; ++os)
#pragma unroll
                for (int ms = 0; ms < 4; ++ms)
                    acc[os][ms] = __builtin_amdgcn_mfma_f32_16x16x32_bf16(a[os], b[ms], acc[os][ms], 0, 0, 0);
        }
        __syncthreads();
    }

#pragma unroll
    for (int os = 0; os < 4; ++os)
#pragma unroll
        for (int ms = 0; ms < 4; ++ms) {
            int m = m_base + wm * 64 + ms * 16 + l15;
            int bb = m / HW2;
            int hw = m - bb * HW2;
            int o = o_base + wo * 64 + os * 16 + g * 4;
            float* dst = out + ((size_t)bb * NO + o) * HW2 + hw;
            f32x4 v = acc[os][ms];
            dst[0 * HW2] = v[0];
            dst[1 * HW2] = v[1];
            dst[2 * HW2] = v[2];
            dst[3 * HW2] = v[3];
        }
}

extern "C" void kernel_launch(void* const* d_in, const int* in_sizes, int n_in,
                              void* d_out, int out_size, void* d_ws, size_t ws_size,
                              hipStream_t stream) {
    const float* x1   = (const float*)d_in[0];
    const float* x3   = (const float*)d_in[1];
    const float* x5   = (const float*)d_in[2];
    const float* W    = (const float*)d_in[3];
    const int*   idx  = (const int*)d_in[4];
    const int*   offh = (const int*)d_in[5];
    const int*   offw = (const int*)d_in[6];
    float* out = (float*)d_out;

    char* ws = (char*)d_ws;
    __bf16* fT     = (__bf16*)(ws);              // 19,267,584 B
    __bf16* feats  = (__bf16*)(ws + 19267584);   // 19,267,584 B
    __bf16* Wb     = (__bf16*)(ws + 38535168);   // 589,824 B
    int*    cnt    = (int*)   (ws + 39124992);   // 6,144 B
    u32*    bucket = (u32*)   (ws + 39131136);   // 786,432 B

    wconv_kernel<<<(NO * NC) / 256, 256, 0, stream>>>(W, Wb);
    hipMemsetAsync(cnt, 0, 1536 * sizeof(int), stream);
    fill_kernel<<<(NC * HW2) / 256, 256, 0, stream>>>(idx, offh, offw, cnt, bucket);
    scatter_kernel<<<dim3(1536, 4), 256, 0, stream>>>(x1, x3, x5, cnt, bucket, fT);
    ftrans_kernel<<<dim3(HW2, 6), 256, 0, stream>>>(fT, feats);
    gemm_kernel<<<1176, 256, 0, stream>>>(feats, Wb, out);
}